// Round 2
// 273.927 us; speedup vs baseline: 1.1583x; 1.1583x over previous
//
#include <hip/hip_runtime.h>
#include <math.h>

// B=16, Cin=32, Cout=32, H=W=256, m1=m2=16; kept kx in {0..15,240..255}, ky in {0..15}
//
// Fused pipeline (all GEMMs bf16 hi/lo, 3-term MFMA):
//  f12 (block = one (b,ci) image, 512 blocks x 512 thr):
//     F1: T[h][rt][ky] = x[h][w] . B1[w][rt*16+ky]      (M=256,N=32,K=256) -> acc
//     repack acc -> LDS B-frags (k = 2h+rt)
//     F2: X[kx2][bi*16+ky] = A2[kx2][h2] . T            (M=64,N=16,K=512)
//  mix: Y = sum_i X .* W (fp32)                          (unchanged)
//  i12 (block = one (b,co) image, 512 blocks x 512 thr):
//     I1: G[2h+rg][ky] = A3[h2][kx2] . Y[kx2][ky]       (M=512,N=16,K=64) -> acc
//     repack acc -> LDS A-frags (A[h][2ky+ri])
//     I2: out[h][w] = G'[h][ky2] . B2[ky2][w]           (M=256,N=256,K=32)
//
// Twiddle fragments precomputed frag-ordered in global ws (320 slots x 512 ushorts):
//  slot layout: Fr[slot*512 + lane*8 + j]; A-frag: lane holds A[m=lane&15][k=(lane>>4)*8+j]
//  B-frag: lane holds B[k=(lane>>4)*8+j][n=lane&15]   (verified in earlier rounds)
//  slots: [0,32)=F1-B  (tn*16+hl*8+ch)     [32,160)=F2-A (32+mt*32+hl*16+ch)
//         [160,288)=I1-A (160+mtG*4+hl*2+ch)  [288,320)=I2-B (288+nt*2+hl)

#define TWO_PI_256 0.0245436926f

typedef short short8 __attribute__((ext_vector_type(8)));
typedef float f32x4  __attribute__((ext_vector_type(4)));

__device__ __forceinline__ ushort f2bf(float v) {
    unsigned u = __float_as_uint(v);
    u += 0x7FFFu + ((u >> 16) & 1u);
    return (ushort)(u >> 16);
}
__device__ __forceinline__ float bf2f(ushort h) {
    return __uint_as_float(((unsigned)h) << 16);
}

// ---------------- init: all twiddle fragments ----------------
__global__ void init_frags(ushort* __restrict__ Fr) {
    const int s = blockIdx.x;          // slot 0..319
    const int lane = threadIdx.x;      // 0..63
    const int q = lane >> 4, n = lane & 15;
    for (int j = 0; j < 8; ++j) {
        float v = 0.f;
        int hl;
        if (s < 32) {                          // F1 B: B[w][tn*16+ky]
            int tn = s >> 4; hl = (s >> 3) & 1; int ch = s & 7;
            int w = ch * 32 + q * 8 + j, ky = n;
            float sn, cs; __sincosf((float)((w * ky) & 255) * TWO_PI_256, &sn, &cs);
            v = tn == 0 ? cs : -sn;            // e^{-i}: Tr=+cos, Ti=-sin
        } else if (s < 160) {                  // F2 A: A[m][k], m=kxi*2+rx, k=h*2+rt
            int s2 = s - 32; int mt = s2 >> 5; hl = (s2 >> 4) & 1; int ch = s2 & 15;
            int m = mt * 16 + n, k = ch * 32 + q * 8 + j;
            int kxi = m >> 1, rx = m & 1, h = k >> 1, rt = k & 1;
            int r = kxi + (kxi >= 16 ? 224 : 0);
            float sn, cs; __sincosf((float)((r * h) & 255) * TWO_PI_256, &sn, &cs);
            v = (rx == 0) ? (rt == 0 ? cs : sn) : (rt == 0 ? -sn : cs);
        } else if (s < 288) {                  // I1 A: A[m][k], m=h*2+rg, k=kxi*2+ry (x 1/65536)
            int s3 = s - 160; int mtG = s3 >> 2; hl = (s3 >> 1) & 1; int ch = s3 & 1;
            int m = mtG * 16 + n, k = ch * 32 + q * 8 + j;
            int h = m >> 1, rg = m & 1, kxi = k >> 1, ry = k & 1;
            int r = kxi + (kxi >= 16 ? 224 : 0);
            float sn, cs; __sincosf((float)((r * h) & 255) * TWO_PI_256, &sn, &cs);
            v = ((rg == 0) ? (ry == 0 ? cs : -sn) : (ry == 0 ? sn : cs)) * (1.0f / 65536.0f);
        } else {                               // I2 B: B[k][w], k=ky*2+ri
            int s4 = s - 288; int nt = s4 >> 1; hl = s4 & 1;
            int k = q * 8 + j, w = nt * 16 + n;
            int ky = k >> 1, ri = k & 1;
            float sn, cs; __sincosf((float)((w * ky) & 255) * TWO_PI_256, &sn, &cs);
            v = (ky == 0) ? (ri ? 0.f : 1.f) : (ri ? -2.f * sn : 2.f * cs);
        }
        ushort hi = f2bf(v);
        Fr[s * 512 + lane * 8 + j] = hl == 0 ? hi : f2bf(v - bf2f(hi));
    }
}

// ---------------- f12: x -> X (fused F1 + F2, one (b,ci) image per block) ----------------
__global__ __launch_bounds__(512) void f12_gemm(const float* __restrict__ x,
                                                const ushort* __restrict__ Fr,
                                                float* __restrict__ X) {
    // 32 KB LDS: during F1 = Ah[256*32] + Al[256*32]; after = Ts[16 chunks][hi/lo][512]
    __shared__ ushort LDS[16384];
    ushort* Ah = LDS;
    ushort* Al = LDS + 8192;
    ushort* Ts = LDS;

    const int t = threadIdx.x, bi = blockIdx.x;          // bi = b*32 + ci
    const int lane = t & 63, w = t >> 6;                 // 8 waves
    const int q = lane >> 4, n = lane & 15;
    const int srow = t >> 3, sw4 = t & 7;
    const float* xb = x + (size_t)bi * 65536;

    f32x4 acc[2][2];                                     // [mt][tn]; wave w owns rows [w*32, w*32+32)
    #pragma unroll
    for (int a = 0; a < 2; ++a)
        #pragma unroll
        for (int bb = 0; bb < 2; ++bb) acc[a][bb] = (f32x4){0.f, 0.f, 0.f, 0.f};

    for (int ch = 0; ch < 8; ++ch) {
        __syncthreads();
        #pragma unroll
        for (int m = 0; m < 4; ++m) {
            const int row = srow + 64 * m;
            float4 v = *(const float4*)(xb + (size_t)row * 256 + ch * 32 + sw4 * 4);
            ushort h0_ = f2bf(v.x), h1 = f2bf(v.y), h2 = f2bf(v.z), h3 = f2bf(v.w);
            *(ushort4*)&Ah[row * 32 + sw4 * 4] = make_ushort4(h0_, h1, h2, h3);
            *(ushort4*)&Al[row * 32 + sw4 * 4] = make_ushort4(f2bf(v.x - bf2f(h0_)), f2bf(v.y - bf2f(h1)),
                                                              f2bf(v.z - bf2f(h2)), f2bf(v.w - bf2f(h3)));
        }
        __syncthreads();

        short8 bh0 = *(const short8*)&Fr[(size_t)(0  + ch) * 512 + lane * 8];
        short8 bl0 = *(const short8*)&Fr[(size_t)(8  + ch) * 512 + lane * 8];
        short8 bh1 = *(const short8*)&Fr[(size_t)(16 + ch) * 512 + lane * 8];
        short8 bl1 = *(const short8*)&Fr[(size_t)(24 + ch) * 512 + lane * 8];

        #pragma unroll
        for (int mt = 0; mt < 2; ++mt) {
            const int row = w * 32 + mt * 16 + n;
            short8 ah = *(const short8*)&Ah[row * 32 + q * 8];
            short8 al = *(const short8*)&Al[row * 32 + q * 8];
            acc[mt][0] = __builtin_amdgcn_mfma_f32_16x16x32_bf16(al, bh0, acc[mt][0], 0, 0, 0);
            acc[mt][0] = __builtin_amdgcn_mfma_f32_16x16x32_bf16(ah, bl0, acc[mt][0], 0, 0, 0);
            acc[mt][0] = __builtin_amdgcn_mfma_f32_16x16x32_bf16(ah, bh0, acc[mt][0], 0, 0, 0);
            acc[mt][1] = __builtin_amdgcn_mfma_f32_16x16x32_bf16(al, bh1, acc[mt][1], 0, 0, 0);
            acc[mt][1] = __builtin_amdgcn_mfma_f32_16x16x32_bf16(ah, bl1, acc[mt][1], 0, 0, 0);
            acc[mt][1] = __builtin_amdgcn_mfma_f32_16x16x32_bf16(ah, bh1, acc[mt][1], 0, 0, 0);
        }
    }

    // repack acc (T values) into F2 B-frag layout: k = 2h+rt; h = w*32+mt*16+q*4+r
    //  -> chunk c = w*2+mt, k%32 = q*8 + (2r+rt): j' = 2r+rt is contiguous -> one short8 per mt
    __syncthreads();
    #pragma unroll
    for (int mt = 0; mt < 2; ++mt) {
        ushort h8[8], l8[8];
        #pragma unroll
        for (int j = 0; j < 8; ++j) {
            float v = acc[mt][j & 1][j >> 1];
            h8[j] = f2bf(v);
            l8[j] = f2bf(v - bf2f(h8[j]));
        }
        const int c = w * 2 + mt;
        *(short8*)&Ts[c * 1024 + lane * 8]       = *(short8*)h8;
        *(short8*)&Ts[c * 1024 + 512 + lane * 8] = *(short8*)l8;
    }
    __syncthreads();

    // F2: M=64 (4 m-tiles, waves 0..3), N=16 (this image's 16 cols), K=512 (16 chunks)
    if (w < 4) {
        const int mt2 = w;
        f32x4 a2 = (f32x4){0.f, 0.f, 0.f, 0.f};
        #pragma unroll
        for (int c2 = 0; c2 < 16; ++c2) {
            short8 bh = *(const short8*)&Ts[c2 * 1024 + lane * 8];
            short8 bl = *(const short8*)&Ts[c2 * 1024 + 512 + lane * 8];
            short8 ah = *(const short8*)&Fr[(size_t)(32 + mt2 * 32 + c2) * 512 + lane * 8];
            short8 al = *(const short8*)&Fr[(size_t)(32 + mt2 * 32 + 16 + c2) * 512 + lane * 8];
            a2 = __builtin_amdgcn_mfma_f32_16x16x32_bf16(al, bh, a2, 0, 0, 0);
            a2 = __builtin_amdgcn_mfma_f32_16x16x32_bf16(ah, bl, a2, 0, 0, 0);
            a2 = __builtin_amdgcn_mfma_f32_16x16x32_bf16(ah, bh, a2, 0, 0, 0);
        }
        #pragma unroll
        for (int r = 0; r < 4; ++r)
            X[(size_t)(mt2 * 16 + q * 4 + r) * 8192 + bi * 16 + n] = a2[r];
    }
}

// ---------------- mix (fp32) ----------------
__global__ __launch_bounds__(256) void mix(const float* __restrict__ X,
                                           const float* __restrict__ w1r_, const float* __restrict__ w1i_,
                                           const float* __restrict__ w2r_, const float* __restrict__ w2i_,
                                           float* __restrict__ Y) {
    int gid = blockIdx.x * 256 + threadIdx.x;
    int ky = gid & 15, kxi = (gid >> 4) & 31, o = (gid >> 9) & 31, b = gid >> 14;
    const float* wr = (kxi < 16) ? w1r_ : w2r_;
    const float* wi = (kxi < 16) ? w1i_ : w2i_;
    int xx = kxi & 15;
    const float* Xr = X + (size_t)(kxi * 2) * 8192 + b * 512 + ky;
    const float* Xi = Xr + 8192;
    const float* wrp = wr + (size_t)(o * 16 + xx) * 16 + ky;
    const float* wip = wi + (size_t)(o * 16 + xx) * 16 + ky;
    float yr = 0.f, yi = 0.f;
    #pragma unroll 8
    for (int i = 0; i < 32; ++i) {
        float xr = Xr[i * 16], xim = Xi[i * 16];
        float wre = wrp[(size_t)i * 8192], wim = wip[(size_t)i * 8192];
        yr = fmaf(xr, wre, fmaf(-xim, wim, yr));
        yi = fmaf(xr, wim, fmaf( xim, wre, yi));
    }
    size_t yb = (size_t)(kxi * 2) * 8192 + b * 512 + o * 16 + ky;
    Y[yb] = yr;
    Y[yb + 8192] = yi;
}

// ---------------- i12: Y -> out (fused I1 + I2, one (b,co) image per block) ----------------
__global__ __launch_bounds__(512) void i12_gemm(const float* __restrict__ Yb,
                                                const ushort* __restrict__ Fr,
                                                float* __restrict__ out) {
    __shared__ ushort Bs[2048];       // Y as I1 B-frags: [c=2][hi/lo][512]
    __shared__ ushort As[16384];      // G as I2 A-frags: [ht=16][hi/lo][512]
    const int t = threadIdx.x, bo = blockIdx.x;          // bo = b*32 + o
    const int lane = t & 63, w = t >> 6;
    const int q = lane >> 4, n = lane & 15;
    const int b = bo >> 5, o = bo & 31;

    // stage Y slice [64 k][16 ky] into I1 B-frag layout
    if (t < 256) {
        const int k = t >> 2, e4 = t & 3;
        float4 v = *(const float4*)&Yb[(size_t)k * 8192 + b * 512 + o * 16 + e4 * 4];
        const int c = k >> 5, q2 = (k >> 3) & 3, j2 = k & 7;
        float vv[4] = {v.x, v.y, v.z, v.w};
        #pragma unroll
        for (int ee = 0; ee < 4; ++ee) {
            const int ky = e4 * 4 + ee;
            ushort hi = f2bf(vv[ee]);
            Bs[c * 1024 + (q2 * 16 + ky) * 8 + j2]       = hi;
            Bs[c * 1024 + 512 + (q2 * 16 + ky) * 8 + j2] = f2bf(vv[ee] - bf2f(hi));
        }
    }
    __syncthreads();

    // I1: M=512 -> 32 m-tiles over 8 waves (4 each), N=16, K=64 (2 chunks)
    f32x4 g[4];
    #pragma unroll
    for (int mi = 0; mi < 4; ++mi) g[mi] = (f32x4){0.f, 0.f, 0.f, 0.f};
    #pragma unroll
    for (int ch = 0; ch < 2; ++ch) {
        short8 bh = *(const short8*)&Bs[ch * 1024 + lane * 8];
        short8 bl = *(const short8*)&Bs[ch * 1024 + 512 + lane * 8];
        #pragma unroll
        for (int mi = 0; mi < 4; ++mi) {
            const int mtG = w * 4 + mi;
            short8 ah = *(const short8*)&Fr[(size_t)(160 + mtG * 4 + ch) * 512 + lane * 8];
            short8 al = *(const short8*)&Fr[(size_t)(160 + mtG * 4 + 2 + ch) * 512 + lane * 8];
            g[mi] = __builtin_amdgcn_mfma_f32_16x16x32_bf16(al, bh, g[mi], 0, 0, 0);
            g[mi] = __builtin_amdgcn_mfma_f32_16x16x32_bf16(ah, bl, g[mi], 0, 0, 0);
            g[mi] = __builtin_amdgcn_mfma_f32_16x16x32_bf16(ah, bh, g[mi], 0, 0, 0);
        }
    }

    // repack G (rows m1 = 2h+ri, col ky=n) into I2 A-frag layout: A[h][k2=2ky+ri]
    // wave w writes h in [w*32, w*32+32) -> exactly the ht tiles {2w, 2w+1} it consumes below
    #pragma unroll
    for (int mi = 0; mi < 4; ++mi)
        #pragma unroll
        for (int r = 0; r < 4; ++r) {
            const int m1 = (w * 4 + mi) * 16 + q * 4 + r;
            const int h = m1 >> 1, ri = m1 & 1;
            const int k2 = 2 * n + ri;
            const int ht = h >> 4, hr = h & 15;
            const int ad = ((k2 >> 3) * 16 + hr) * 8 + (k2 & 7);
            const float v = g[mi][r];
            const ushort hi = f2bf(v);
            As[ht * 1024 + ad]       = hi;
            As[ht * 1024 + 512 + ad] = f2bf(v - bf2f(hi));
        }
    __syncthreads();

    // I2: M=256 (16 m-tiles over 8 waves, 2 each), N=256 (16 n-tiles), K=32 (1 chunk)
    #pragma unroll
    for (int mi2 = 0; mi2 < 2; ++mi2) {
        const int ht2 = w * 2 + mi2;
        short8 ah = *(const short8*)&As[ht2 * 1024 + lane * 8];
        short8 al = *(const short8*)&As[ht2 * 1024 + 512 + lane * 8];
        f32x4 a3[16];
        #pragma unroll
        for (int nt = 0; nt < 16; ++nt) a3[nt] = (f32x4){0.f, 0.f, 0.f, 0.f};
        #pragma unroll
        for (int nt = 0; nt < 16; ++nt) {
            short8 bh = *(const short8*)&Fr[(size_t)(288 + nt * 2) * 512 + lane * 8];
            short8 bl = *(const short8*)&Fr[(size_t)(288 + nt * 2 + 1) * 512 + lane * 8];
            a3[nt] = __builtin_amdgcn_mfma_f32_16x16x32_bf16(al, bh, a3[nt], 0, 0, 0);
            a3[nt] = __builtin_amdgcn_mfma_f32_16x16x32_bf16(ah, bl, a3[nt], 0, 0, 0);
            a3[nt] = __builtin_amdgcn_mfma_f32_16x16x32_bf16(ah, bh, a3[nt], 0, 0, 0);
        }
        const size_t Rrow = (size_t)bo * 256 + ht2 * 16 + q * 4;
        #pragma unroll
        for (int nt = 0; nt < 16; ++nt)
            #pragma unroll
            for (int r = 0; r < 4; ++r)
                out[(Rrow + r) * 256 + nt * 16 + n] = a3[nt][r];
    }
}

extern "C" void kernel_launch(void* const* d_in, const int* in_sizes, int n_in,
                              void* d_out, int out_size, void* d_ws, size_t ws_size,
                              hipStream_t stream) {
    const float* x   = (const float*)d_in[0];
    const float* w1r = (const float*)d_in[1];
    const float* w1i = (const float*)d_in[2];
    const float* w2r = (const float*)d_in[3];
    const float* w2i = (const float*)d_in[4];
    float* out = (float*)d_out;

    // ws: Fr 320KB @0 | X 2MB @1MB | Y 2MB
    ushort* Fr = (ushort*)d_ws;
    float*  X  = (float*)((char*)d_ws + (1u << 20));
    float*  Yb = X + (size_t)524288;

    init_frags<<<320,  64,  0, stream>>>(Fr);
    f12_gemm  <<<512,  512, 0, stream>>>(x, Fr, X);
    mix       <<<1024, 256, 0, stream>>>(X, w1r, w1i, w2r, w2i, Yb);
    i12_gemm  <<<512,  512, 0, stream>>>(Yb, Fr, out);
}

// Round 3
// 269.926 us; speedup vs baseline: 1.1755x; 1.0148x over previous
//
#include <hip/hip_runtime.h>
#include <math.h>

// B=16, Cin=32, Cout=32, H=W=256, m1=m2=16; kept kx in {0..15,240..255}, ky in {0..15}
//
// Fused pipeline (all GEMMs bf16 hi/lo, 3-term MFMA):
//  f12 (block = one (b,ci) image, 512 blocks x 512 thr, reg-prefetch chunk loop):
//     F1: T[h][rt][ky] = x[h][w] . B1[w][rt*16+ky]      (M=256,N=32,K=256) -> acc
//     repack acc -> LDS B-frags (k = 2h+rt)
//     F2: X[kx2][bi*16+ky] = A2[kx2][h2] . T            (M=64,N=16,K=512)
//  i12 (block = one (b,co) image, 512 blocks x 512 thr):
//     mix prologue: thread (kxi,ky) computes Yc = sum_i Xc .* Wc  (fp32, X/W from L2)
//                   -> writes straight into I1 B-frag LDS layout
//     I1: G[2h+rg][ky] = A3[h2][kx2] . Y[kx2][ky]       (M=512,N=16,K=64) -> acc
//     repack acc -> LDS A-frags (A[h][2ky+ri])
//     I2: out[h][w] = G'[h][ky2] . B2[ky2][w]           (M=256,N=256,K=32)
//
// Twiddle fragments precomputed frag-ordered in global ws (320 slots x 512 ushorts):
//  slot layout: Fr[slot*512 + lane*8 + j]; A-frag: lane holds A[m=lane&15][k=(lane>>4)*8+j]
//  B-frag: lane holds B[k=(lane>>4)*8+j][n=lane&15]   (verified in earlier rounds)
//  slots: [0,32)=F1-B  (tn*16+hl*8+ch)     [32,160)=F2-A (32+mt*32+hl*16+ch)
//         [160,288)=I1-A (160+mtG*4+hl*2+ch)  [288,320)=I2-B (288+nt*2+hl)

#define TWO_PI_256 0.0245436926f

typedef short short8 __attribute__((ext_vector_type(8)));
typedef float f32x4  __attribute__((ext_vector_type(4)));

__device__ __forceinline__ ushort f2bf(float v) {
    unsigned u = __float_as_uint(v);
    u += 0x7FFFu + ((u >> 16) & 1u);
    return (ushort)(u >> 16);
}
__device__ __forceinline__ float bf2f(ushort h) {
    return __uint_as_float(((unsigned)h) << 16);
}

// ---------------- init: all twiddle fragments ----------------
__global__ void init_frags(ushort* __restrict__ Fr) {
    const int s = blockIdx.x;          // slot 0..319
    const int lane = threadIdx.x;      // 0..63
    const int q = lane >> 4, n = lane & 15;
    for (int j = 0; j < 8; ++j) {
        float v = 0.f;
        int hl;
        if (s < 32) {                          // F1 B: B[w][tn*16+ky]
            int tn = s >> 4; hl = (s >> 3) & 1; int ch = s & 7;
            int w = ch * 32 + q * 8 + j, ky = n;
            float sn, cs; __sincosf((float)((w * ky) & 255) * TWO_PI_256, &sn, &cs);
            v = tn == 0 ? cs : -sn;            // e^{-i}: Tr=+cos, Ti=-sin
        } else if (s < 160) {                  // F2 A: A[m][k], m=kxi*2+rx, k=h*2+rt
            int s2 = s - 32; int mt = s2 >> 5; hl = (s2 >> 4) & 1; int ch = s2 & 15;
            int m = mt * 16 + n, k = ch * 32 + q * 8 + j;
            int kxi = m >> 1, rx = m & 1, h = k >> 1, rt = k & 1;
            int r = kxi + (kxi >= 16 ? 224 : 0);
            float sn, cs; __sincosf((float)((r * h) & 255) * TWO_PI_256, &sn, &cs);
            v = (rx == 0) ? (rt == 0 ? cs : sn) : (rt == 0 ? -sn : cs);
        } else if (s < 288) {                  // I1 A: A[m][k], m=h*2+rg, k=kxi*2+ry (x 1/65536)
            int s3 = s - 160; int mtG = s3 >> 2; hl = (s3 >> 1) & 1; int ch = s3 & 1;
            int m = mtG * 16 + n, k = ch * 32 + q * 8 + j;
            int h = m >> 1, rg = m & 1, kxi = k >> 1, ry = k & 1;
            int r = kxi + (kxi >= 16 ? 224 : 0);
            float sn, cs; __sincosf((float)((r * h) & 255) * TWO_PI_256, &sn, &cs);
            v = ((rg == 0) ? (ry == 0 ? cs : -sn) : (ry == 0 ? sn : cs)) * (1.0f / 65536.0f);
        } else {                               // I2 B: B[k][w], k=ky*2+ri
            int s4 = s - 288; int nt = s4 >> 1; hl = s4 & 1;
            int k = q * 8 + j, w = nt * 16 + n;
            int ky = k >> 1, ri = k & 1;
            float sn, cs; __sincosf((float)((w * ky) & 255) * TWO_PI_256, &sn, &cs);
            v = (ky == 0) ? (ri ? 0.f : 1.f) : (ri ? -2.f * sn : 2.f * cs);
        }
        ushort hi = f2bf(v);
        Fr[s * 512 + lane * 8 + j] = hl == 0 ? hi : f2bf(v - bf2f(hi));
    }
}

// ---------------- f12: x -> X (fused F1 + F2, one (b,ci) image per block) ----------------
__global__ __launch_bounds__(512) void f12_gemm(const float* __restrict__ x,
                                                const ushort* __restrict__ Fr,
                                                float* __restrict__ X) {
    // 32 KB LDS: during F1 = Ah[256*32] + Al[256*32]; after = Ts[16 chunks][hi/lo][512]
    __shared__ ushort LDS[16384];
    ushort* Ah = LDS;
    ushort* Al = LDS + 8192;
    ushort* Ts = LDS;

    const int t = threadIdx.x, bi = blockIdx.x;          // bi = b*32 + ci
    const int lane = t & 63, w = t >> 6;                 // 8 waves
    const int q = lane >> 4, n = lane & 15;
    const int srow = t >> 3, sw4 = t & 7;
    const float* xb = x + (size_t)bi * 65536;

    f32x4 acc[2][2];                                     // [mt][tn]; wave w owns rows [w*32, w*32+32)
    #pragma unroll
    for (int a = 0; a < 2; ++a)
        #pragma unroll
        for (int bb = 0; bb < 2; ++bb) acc[a][bb] = (f32x4){0.f, 0.f, 0.f, 0.f};

    // reg-prefetch: vv holds chunk ch's 4 float4 rows; loads for ch+1 issue before MFMA(ch)
    float4 vv[4];
    #pragma unroll
    for (int m = 0; m < 4; ++m)
        vv[m] = *(const float4*)(xb + (size_t)(srow + 64 * m) * 256 + sw4 * 4);

    for (int ch = 0; ch < 8; ++ch) {
        __syncthreads();                                 // prev chunk's consumers done with LDS
        #pragma unroll
        for (int m = 0; m < 4; ++m) {
            const int row = srow + 64 * m;
            float4 v = vv[m];
            ushort h0_ = f2bf(v.x), h1 = f2bf(v.y), h2 = f2bf(v.z), h3 = f2bf(v.w);
            *(ushort4*)&Ah[row * 32 + sw4 * 4] = make_ushort4(h0_, h1, h2, h3);
            *(ushort4*)&Al[row * 32 + sw4 * 4] = make_ushort4(f2bf(v.x - bf2f(h0_)), f2bf(v.y - bf2f(h1)),
                                                              f2bf(v.z - bf2f(h2)), f2bf(v.w - bf2f(h3)));
        }
        __syncthreads();

        if (ch < 7) {
            #pragma unroll
            for (int m = 0; m < 4; ++m)
                vv[m] = *(const float4*)(xb + (size_t)(srow + 64 * m) * 256 + (ch + 1) * 32 + sw4 * 4);
        }

        short8 bh0 = *(const short8*)&Fr[(size_t)(0  + ch) * 512 + lane * 8];
        short8 bl0 = *(const short8*)&Fr[(size_t)(8  + ch) * 512 + lane * 8];
        short8 bh1 = *(const short8*)&Fr[(size_t)(16 + ch) * 512 + lane * 8];
        short8 bl1 = *(const short8*)&Fr[(size_t)(24 + ch) * 512 + lane * 8];

        #pragma unroll
        for (int mt = 0; mt < 2; ++mt) {
            const int row = w * 32 + mt * 16 + n;
            short8 ah = *(const short8*)&Ah[row * 32 + q * 8];
            short8 al = *(const short8*)&Al[row * 32 + q * 8];
            acc[mt][0] = __builtin_amdgcn_mfma_f32_16x16x32_bf16(al, bh0, acc[mt][0], 0, 0, 0);
            acc[mt][0] = __builtin_amdgcn_mfma_f32_16x16x32_bf16(ah, bl0, acc[mt][0], 0, 0, 0);
            acc[mt][0] = __builtin_amdgcn_mfma_f32_16x16x32_bf16(ah, bh0, acc[mt][0], 0, 0, 0);
            acc[mt][1] = __builtin_amdgcn_mfma_f32_16x16x32_bf16(al, bh1, acc[mt][1], 0, 0, 0);
            acc[mt][1] = __builtin_amdgcn_mfma_f32_16x16x32_bf16(ah, bl1, acc[mt][1], 0, 0, 0);
            acc[mt][1] = __builtin_amdgcn_mfma_f32_16x16x32_bf16(ah, bh1, acc[mt][1], 0, 0, 0);
        }
    }

    // repack acc (T values) into F2 B-frag layout: k = 2h+rt; h = w*32+mt*16+q*4+r
    //  -> chunk c = w*2+mt, k%32 = q*8 + (2r+rt): j' = 2r+rt is contiguous -> one short8 per mt
    __syncthreads();
    #pragma unroll
    for (int mt = 0; mt < 2; ++mt) {
        ushort h8[8], l8[8];
        #pragma unroll
        for (int j = 0; j < 8; ++j) {
            float v = acc[mt][j & 1][j >> 1];
            h8[j] = f2bf(v);
            l8[j] = f2bf(v - bf2f(h8[j]));
        }
        const int c = w * 2 + mt;
        *(short8*)&Ts[c * 1024 + lane * 8]       = *(short8*)h8;
        *(short8*)&Ts[c * 1024 + 512 + lane * 8] = *(short8*)l8;
    }
    __syncthreads();

    // F2: M=64 (4 m-tiles, waves 0..3), N=16 (this image's 16 cols), K=512 (16 chunks)
    if (w < 4) {
        const int mt2 = w;
        f32x4 a2 = (f32x4){0.f, 0.f, 0.f, 0.f};
        #pragma unroll
        for (int c2 = 0; c2 < 16; ++c2) {
            short8 bh = *(const short8*)&Ts[c2 * 1024 + lane * 8];
            short8 bl = *(const short8*)&Ts[c2 * 1024 + 512 + lane * 8];
            short8 ah = *(const short8*)&Fr[(size_t)(32 + mt2 * 32 + c2) * 512 + lane * 8];
            short8 al = *(const short8*)&Fr[(size_t)(32 + mt2 * 32 + 16 + c2) * 512 + lane * 8];
            a2 = __builtin_amdgcn_mfma_f32_16x16x32_bf16(al, bh, a2, 0, 0, 0);
            a2 = __builtin_amdgcn_mfma_f32_16x16x32_bf16(ah, bl, a2, 0, 0, 0);
            a2 = __builtin_amdgcn_mfma_f32_16x16x32_bf16(ah, bh, a2, 0, 0, 0);
        }
        #pragma unroll
        for (int r = 0; r < 4; ++r)
            X[(size_t)(mt2 * 16 + q * 4 + r) * 8192 + bi * 16 + n] = a2[r];
    }
}

// ---------------- i12: X -> out (fused mix + I1 + I2, one (b,co) image per block) ----------------
__global__ __launch_bounds__(512) void i12_gemm(const float* __restrict__ X,
                                                const float* __restrict__ w1r_, const float* __restrict__ w1i_,
                                                const float* __restrict__ w2r_, const float* __restrict__ w2i_,
                                                const ushort* __restrict__ Fr,
                                                float* __restrict__ out) {
    __shared__ ushort Bs[2048];       // Y as I1 B-frags: [c=2][hi/lo][512]
    __shared__ ushort As[16384];      // G as I2 A-frags: [ht=16][hi/lo][512]
    const int t = threadIdx.x, bo = blockIdx.x;          // bo = b*32 + o
    const int lane = t & 63, w = t >> 6;
    const int q = lane >> 4, n = lane & 15;
    const int b = bo >> 5, o = bo & 31;

    // fused mix: thread t owns frequency (kxi = t>>4, ky = t&15); computes Yc = sum_i Xc .* Wc
    // (same fp32 fma order as the old standalone mix kernel -> bit-identical Y)
    {
        const int kxi = t >> 4, ky = t & 15;
        const float* wr = (kxi < 16) ? w1r_ : w2r_;
        const float* wi = (kxi < 16) ? w1i_ : w2i_;
        const int xx = kxi & 15;
        const float* Xr = X + (size_t)(kxi * 2) * 8192 + b * 512 + ky;
        const float* Xi = Xr + 8192;
        const float* wrp = wr + (size_t)(o * 16 + xx) * 16 + ky;
        const float* wip = wi + (size_t)(o * 16 + xx) * 16 + ky;
        float yr = 0.f, yi = 0.f;
        #pragma unroll 8
        for (int i = 0; i < 32; ++i) {
            float xr = Xr[i * 16], xim = Xi[i * 16];
            float wre = wrp[(size_t)i * 8192], wim = wip[(size_t)i * 8192];
            yr = fmaf(xr, wre, fmaf(-xim, wim, yr));
            yi = fmaf(xr, wim, fmaf( xim, wre, yi));
        }
        // write (k=2kxi -> yr) and (k=2kxi+1 -> yi) into I1 B-frag layout
        const int k0 = kxi * 2;
        const int c = k0 >> 5, q2 = (k0 >> 3) & 3, j2 = k0 & 7;   // k0 even -> k0+1 shares c,q2
        ushort hr_ = f2bf(yr);
        Bs[c * 1024 + (q2 * 16 + ky) * 8 + j2]           = hr_;
        Bs[c * 1024 + 512 + (q2 * 16 + ky) * 8 + j2]     = f2bf(yr - bf2f(hr_));
        ushort hi_ = f2bf(yi);
        Bs[c * 1024 + (q2 * 16 + ky) * 8 + j2 + 1]       = hi_;
        Bs[c * 1024 + 512 + (q2 * 16 + ky) * 8 + j2 + 1] = f2bf(yi - bf2f(hi_));
    }
    __syncthreads();

    // I1: M=512 -> 32 m-tiles over 8 waves (4 each), N=16, K=64 (2 chunks)
    f32x4 g[4];
    #pragma unroll
    for (int mi = 0; mi < 4; ++mi) g[mi] = (f32x4){0.f, 0.f, 0.f, 0.f};
    #pragma unroll
    for (int ch = 0; ch < 2; ++ch) {
        short8 bh = *(const short8*)&Bs[ch * 1024 + lane * 8];
        short8 bl = *(const short8*)&Bs[ch * 1024 + 512 + lane * 8];
        #pragma unroll
        for (int mi = 0; mi < 4; ++mi) {
            const int mtG = w * 4 + mi;
            short8 ah = *(const short8*)&Fr[(size_t)(160 + mtG * 4 + ch) * 512 + lane * 8];
            short8 al = *(const short8*)&Fr[(size_t)(160 + mtG * 4 + 2 + ch) * 512 + lane * 8];
            g[mi] = __builtin_amdgcn_mfma_f32_16x16x32_bf16(al, bh, g[mi], 0, 0, 0);
            g[mi] = __builtin_amdgcn_mfma_f32_16x16x32_bf16(ah, bl, g[mi], 0, 0, 0);
            g[mi] = __builtin_amdgcn_mfma_f32_16x16x32_bf16(ah, bh, g[mi], 0, 0, 0);
        }
    }

    // repack G (rows m1 = 2h+ri, col ky=n) into I2 A-frag layout: A[h][k2=2ky+ri]
    // wave w writes h in [w*32, w*32+32) -> exactly the ht tiles {2w, 2w+1} it consumes below
    #pragma unroll
    for (int mi = 0; mi < 4; ++mi)
        #pragma unroll
        for (int r = 0; r < 4; ++r) {
            const int m1 = (w * 4 + mi) * 16 + q * 4 + r;
            const int h = m1 >> 1, ri = m1 & 1;
            const int k2 = 2 * n + ri;
            const int ht = h >> 4, hr = h & 15;
            const int ad = ((k2 >> 3) * 16 + hr) * 8 + (k2 & 7);
            const float v = g[mi][r];
            const ushort hi = f2bf(v);
            As[ht * 1024 + ad]       = hi;
            As[ht * 1024 + 512 + ad] = f2bf(v - bf2f(hi));
        }
    __syncthreads();

    // I2: M=256 (16 m-tiles over 8 waves, 2 each), N=256 (16 n-tiles), K=32 (1 chunk)
    #pragma unroll
    for (int mi2 = 0; mi2 < 2; ++mi2) {
        const int ht2 = w * 2 + mi2;
        short8 ah = *(const short8*)&As[ht2 * 1024 + lane * 8];
        short8 al = *(const short8*)&As[ht2 * 1024 + 512 + lane * 8];
        f32x4 a3[16];
        #pragma unroll
        for (int nt = 0; nt < 16; ++nt) a3[nt] = (f32x4){0.f, 0.f, 0.f, 0.f};
        #pragma unroll
        for (int nt = 0; nt < 16; ++nt) {
            short8 bh = *(const short8*)&Fr[(size_t)(288 + nt * 2) * 512 + lane * 8];
            short8 bl = *(const short8*)&Fr[(size_t)(288 + nt * 2 + 1) * 512 + lane * 8];
            a3[nt] = __builtin_amdgcn_mfma_f32_16x16x32_bf16(al, bh, a3[nt], 0, 0, 0);
            a3[nt] = __builtin_amdgcn_mfma_f32_16x16x32_bf16(ah, bl, a3[nt], 0, 0, 0);
            a3[nt] = __builtin_amdgcn_mfma_f32_16x16x32_bf16(ah, bh, a3[nt], 0, 0, 0);
        }
        const size_t Rrow = (size_t)bo * 256 + ht2 * 16 + q * 4;
        #pragma unroll
        for (int nt = 0; nt < 16; ++nt)
            #pragma unroll
            for (int r = 0; r < 4; ++r)
                out[(Rrow + r) * 256 + nt * 16 + n] = a3[nt][r];
    }
}

extern "C" void kernel_launch(void* const* d_in, const int* in_sizes, int n_in,
                              void* d_out, int out_size, void* d_ws, size_t ws_size,
                              hipStream_t stream) {
    const float* x   = (const float*)d_in[0];
    const float* w1r = (const float*)d_in[1];
    const float* w1i = (const float*)d_in[2];
    const float* w2r = (const float*)d_in[3];
    const float* w2i = (const float*)d_in[4];
    float* out = (float*)d_out;

    // ws: Fr 320KB @0 | X 2MB @1MB
    ushort* Fr = (ushort*)d_ws;
    float*  X  = (float*)((char*)d_ws + (1u << 20));

    init_frags<<<320,  64,  0, stream>>>(Fr);
    f12_gemm  <<<512,  512, 0, stream>>>(x, Fr, X);
    i12_gemm  <<<512,  512, 0, stream>>>(X, w1r, w1i, w2r, w2i, Fr, out);
}

// Round 7
// 269.245 us; speedup vs baseline: 1.1784x; 1.0025x over previous
//
#include <hip/hip_runtime.h>
#include <math.h>

// B=16, Cin=32, Cout=32, H=W=256, m1=m2=16; kept kx in {0..15,240..255}, ky in {0..15}
//
// Fused pipeline (all GEMMs bf16 hi/lo, 3-term MFMA):
//  f12 (block = one (b,ci) image, 512 blocks x 512 thr):
//     F1: T[h][rt][ky] = x[h][w] . B1[w][rt*16+ky]      (M=256,N=32,K=256)
//         A-frags loaded DIRECTLY from global in frag order (32B/lane) -> no LDS, no barriers
//     repack acc -> LDS B-frags (k = 2h+rt), one barrier
//     F2: X[kx2][bi*16+ky] = A2[kx2][h2] . T            (M=64,N=16,K=512)
//  i12 (block = one (b,co) image, 512 blocks x 512 thr):
//     mix prologue: thread (kxi,ky) computes Yc = sum_i Xc .* Wc  (fp32, X/W from L2)
//                   -> writes straight into I1 B-frag LDS layout
//     I1: G[2h+rg][ky] = A3[h2][kx2] . Y[kx2][ky]       (M=512,N=16,K=64) -> acc
//     repack acc -> LDS A-frags (A[h][2ky+ri])
//     I2: out[h][w] = G'[h][ky2] . B2[ky2][w]           (M=256,N=256,K=32)
//
// Twiddle fragments precomputed frag-ordered in global ws (320 slots x 512 ushorts):
//  slot layout: Fr[slot*512 + lane*8 + j]; A-frag: lane holds A[m=lane&15][k=(lane>>4)*8+j]
//  B-frag: lane holds B[k=(lane>>4)*8+j][n=lane&15]   (verified in earlier rounds)
//  slots: [0,32)=F1-B  (tn*16+hl*8+ch)     [32,160)=F2-A (32+mt*32+hl*16+ch)
//         [160,288)=I1-A (160+mtG*4+hl*2+ch)  [288,320)=I2-B (288+nt*2+hl)

#define TWO_PI_256 0.0245436926f

typedef short short8 __attribute__((ext_vector_type(8)));
typedef float f32x4  __attribute__((ext_vector_type(4)));

__device__ __forceinline__ ushort f2bf(float v) {
    unsigned u = __float_as_uint(v);
    u += 0x7FFFu + ((u >> 16) & 1u);
    return (ushort)(u >> 16);
}
__device__ __forceinline__ float bf2f(ushort h) {
    return __uint_as_float(((unsigned)h) << 16);
}

// ---------------- init: all twiddle fragments (one thread per value) ----------------
__global__ __launch_bounds__(512) void init_frags(ushort* __restrict__ Fr) {
    const int s = blockIdx.x;          // slot 0..319
    const int t = threadIdx.x;
    const int lane = t & 63, j = t >> 6;       // j 0..7
    const int q = lane >> 4, n = lane & 15;
    float v = 0.f;
    int hl;
    if (s < 32) {                          // F1 B: B[w][tn*16+ky]
        int tn = s >> 4; hl = (s >> 3) & 1; int ch = s & 7;
        int w = ch * 32 + q * 8 + j, ky = n;
        float sn, cs; __sincosf((float)((w * ky) & 255) * TWO_PI_256, &sn, &cs);
        v = tn == 0 ? cs : -sn;            // e^{-i}: Tr=+cos, Ti=-sin
    } else if (s < 160) {                  // F2 A: A[m][k], m=kxi*2+rx, k=h*2+rt
        int s2 = s - 32; int mt = s2 >> 5; hl = (s2 >> 4) & 1; int ch = s2 & 15;
        int m = mt * 16 + n, k = ch * 32 + q * 8 + j;
        int kxi = m >> 1, rx = m & 1, h = k >> 1, rt = k & 1;
        int r = kxi + (kxi >= 16 ? 224 : 0);
        float sn, cs; __sincosf((float)((r * h) & 255) * TWO_PI_256, &sn, &cs);
        v = (rx == 0) ? (rt == 0 ? cs : sn) : (rt == 0 ? -sn : cs);
    } else if (s < 288) {                  // I1 A: A[m][k], m=h*2+rg, k=kxi*2+ry (x 1/65536)
        int s3 = s - 160; int mtG = s3 >> 2; hl = (s3 >> 1) & 1; int ch = s3 & 1;
        int m = mtG * 16 + n, k = ch * 32 + q * 8 + j;
        int h = m >> 1, rg = m & 1, kxi = k >> 1, ry = k & 1;
        int r = kxi + (kxi >= 16 ? 224 : 0);
        float sn, cs; __sincosf((float)((r * h) & 255) * TWO_PI_256, &sn, &cs);
        v = ((rg == 0) ? (ry == 0 ? cs : -sn) : (ry == 0 ? sn : cs)) * (1.0f / 65536.0f);
    } else {                               // I2 B: B[k][w], k=ky*2+ri
        int s4 = s - 288; int nt = s4 >> 1; hl = s4 & 1;
        int k = q * 8 + j, w = nt * 16 + n;
        int ky = k >> 1, ri = k & 1;
        float sn, cs; __sincosf((float)((w * ky) & 255) * TWO_PI_256, &sn, &cs);
        v = (ky == 0) ? (ri ? 0.f : 1.f) : (ri ? -2.f * sn : 2.f * cs);
    }
    ushort hi = f2bf(v);
    Fr[s * 512 + lane * 8 + j] = hl == 0 ? hi : f2bf(v - bf2f(hi));
}

// ---------------- f12: x -> X (fused F1 + F2, one (b,ci) image per block) ----------------
__global__ __launch_bounds__(512) void f12_gemm(const float* __restrict__ x,
                                                const ushort* __restrict__ Fr,
                                                float* __restrict__ X) {
    // LDS only holds Ts (F2 B-frags): 16 chunks x [hi/lo] x 512 ushorts = 32 KB
    __shared__ ushort Ts[16384];

    const int t = threadIdx.x, bi = blockIdx.x;          // bi = b*32 + ci
    const int lane = t & 63, w = t >> 6;                 // 8 waves
    const int q = lane >> 4, n = lane & 15;
    const float* xb = x + (size_t)bi * 65536;

    f32x4 acc[2][2];                                     // [mt][tn]; wave w owns rows [w*32, w*32+32)
    #pragma unroll
    for (int a = 0; a < 2; ++a)
        #pragma unroll
        for (int bb = 0; bb < 2; ++bb) acc[a][bb] = (f32x4){0.f, 0.f, 0.f, 0.f};

    // F1: barrier-free. Lane loads its A-frag (32 contiguous bytes of x) directly:
    // A[m=lane&15][k=q*8+j] = x[row][ch*32+q*8+j], row = w*32+mt*16+n.
    #pragma unroll
    for (int ch = 0; ch < 8; ++ch) {
        short8 bh0 = *(const short8*)&Fr[(size_t)(0  + ch) * 512 + lane * 8];
        short8 bl0 = *(const short8*)&Fr[(size_t)(8  + ch) * 512 + lane * 8];
        short8 bh1 = *(const short8*)&Fr[(size_t)(16 + ch) * 512 + lane * 8];
        short8 bl1 = *(const short8*)&Fr[(size_t)(24 + ch) * 512 + lane * 8];

        #pragma unroll
        for (int mt = 0; mt < 2; ++mt) {
            const int row = w * 32 + mt * 16 + n;
            const float* xr = xb + (size_t)row * 256 + ch * 32 + q * 8;
            float4 u0 = *(const float4*)xr;
            float4 u1 = *(const float4*)(xr + 4);
            float vals[8] = {u0.x, u0.y, u0.z, u0.w, u1.x, u1.y, u1.z, u1.w};
            ushort h8[8], l8[8];
            #pragma unroll
            for (int j = 0; j < 8; ++j) {
                h8[j] = f2bf(vals[j]);
                l8[j] = f2bf(vals[j] - bf2f(h8[j]));
            }
            short8 ah = *(short8*)h8;
            short8 al = *(short8*)l8;
            acc[mt][0] = __builtin_amdgcn_mfma_f32_16x16x32_bf16(al, bh0, acc[mt][0], 0, 0, 0);
            acc[mt][0] = __builtin_amdgcn_mfma_f32_16x16x32_bf16(ah, bl0, acc[mt][0], 0, 0, 0);
            acc[mt][0] = __builtin_amdgcn_mfma_f32_16x16x32_bf16(ah, bh0, acc[mt][0], 0, 0, 0);
            acc[mt][1] = __builtin_amdgcn_mfma_f32_16x16x32_bf16(al, bh1, acc[mt][1], 0, 0, 0);
            acc[mt][1] = __builtin_amdgcn_mfma_f32_16x16x32_bf16(ah, bl1, acc[mt][1], 0, 0, 0);
            acc[mt][1] = __builtin_amdgcn_mfma_f32_16x16x32_bf16(ah, bh1, acc[mt][1], 0, 0, 0);
        }
    }

    // repack acc (T values) into F2 B-frag layout: k = 2h+rt; h = w*32+mt*16+q*4+r
    //  -> chunk c = w*2+mt, k%32 = q*8 + (2r+rt): j' = 2r+rt is contiguous -> one short8 per mt
    #pragma unroll
    for (int mt = 0; mt < 2; ++mt) {
        ushort h8[8], l8[8];
        #pragma unroll
        for (int j = 0; j < 8; ++j) {
            float v = acc[mt][j & 1][j >> 1];
            h8[j] = f2bf(v);
            l8[j] = f2bf(v - bf2f(h8[j]));
        }
        const int c = w * 2 + mt;
        *(short8*)&Ts[c * 1024 + lane * 8]       = *(short8*)h8;
        *(short8*)&Ts[c * 1024 + 512 + lane * 8] = *(short8*)l8;
    }
    __syncthreads();

    // F2: M=64 (4 m-tiles, waves 0..3), N=16 (this image's 16 cols), K=512 (16 chunks)
    if (w < 4) {
        const int mt2 = w;
        f32x4 a2 = (f32x4){0.f, 0.f, 0.f, 0.f};
        #pragma unroll
        for (int c2 = 0; c2 < 16; ++c2) {
            short8 bh = *(const short8*)&Ts[c2 * 1024 + lane * 8];
            short8 bl = *(const short8*)&Ts[c2 * 1024 + 512 + lane * 8];
            short8 ah = *(const short8*)&Fr[(size_t)(32 + mt2 * 32 + c2) * 512 + lane * 8];
            short8 al = *(const short8*)&Fr[(size_t)(32 + mt2 * 32 + 16 + c2) * 512 + lane * 8];
            a2 = __builtin_amdgcn_mfma_f32_16x16x32_bf16(al, bh, a2, 0, 0, 0);
            a2 = __builtin_amdgcn_mfma_f32_16x16x32_bf16(ah, bl, a2, 0, 0, 0);
            a2 = __builtin_amdgcn_mfma_f32_16x16x32_bf16(ah, bh, a2, 0, 0, 0);
        }
        #pragma unroll
        for (int r = 0; r < 4; ++r)
            X[(size_t)(mt2 * 16 + q * 4 + r) * 8192 + bi * 16 + n] = a2[r];
    }
}

// ---------------- i12: X -> out (fused mix + I1 + I2, one (b,co) image per block) ----------------
__global__ __launch_bounds__(512) void i12_gemm(const float* __restrict__ X,
                                                const float* __restrict__ w1r_, const float* __restrict__ w1i_,
                                                const float* __restrict__ w2r_, const float* __restrict__ w2i_,
                                                const ushort* __restrict__ Fr,
                                                float* __restrict__ out) {
    __shared__ ushort Bs[2048];       // Y as I1 B-frags: [c=2][hi/lo][512]
    __shared__ ushort As[16384];      // G as I2 A-frags: [ht=16][hi/lo][512]
    const int t = threadIdx.x, bo = blockIdx.x;          // bo = b*32 + o
    const int lane = t & 63, w = t >> 6;
    const int q = lane >> 4, n = lane & 15;
    const int b = bo >> 5, o = bo & 31;

    // fused mix: thread t owns frequency (kxi = t>>4, ky = t&15); computes Yc = sum_i Xc .* Wc
    // (same fp32 fma order as the old standalone mix kernel -> bit-identical Y)
    {
        const int kxi = t >> 4, ky = t & 15;
        const float* wr = (kxi < 16) ? w1r_ : w2r_;
        const float* wi = (kxi < 16) ? w1i_ : w2i_;
        const int xx = kxi & 15;
        const float* Xr = X + (size_t)(kxi * 2) * 8192 + b * 512 + ky;
        const float* Xi = Xr + 8192;
        const float* wrp = wr + (size_t)(o * 16 + xx) * 16 + ky;
        const float* wip = wi + (size_t)(o * 16 + xx) * 16 + ky;
        float yr = 0.f, yi = 0.f;
        #pragma unroll 8
        for (int i = 0; i < 32; ++i) {
            float xr = Xr[i * 16], xim = Xi[i * 16];
            float wre = wrp[(size_t)i * 8192], wim = wip[(size_t)i * 8192];
            yr = fmaf(xr, wre, fmaf(-xim, wim, yr));
            yi = fmaf(xr, wim, fmaf( xim, wre, yi));
        }
        // write (k=2kxi -> yr) and (k=2kxi+1 -> yi) into I1 B-frag layout
        const int k0 = kxi * 2;
        const int c = k0 >> 5, q2 = (k0 >> 3) & 3, j2 = k0 & 7;   // k0 even -> k0+1 shares c,q2
        ushort hr_ = f2bf(yr);
        Bs[c * 1024 + (q2 * 16 + ky) * 8 + j2]           = hr_;
        Bs[c * 1024 + 512 + (q2 * 16 + ky) * 8 + j2]     = f2bf(yr - bf2f(hr_));
        ushort hi_ = f2bf(yi);
        Bs[c * 1024 + (q2 * 16 + ky) * 8 + j2 + 1]       = hi_;
        Bs[c * 1024 + 512 + (q2 * 16 + ky) * 8 + j2 + 1] = f2bf(yi - bf2f(hi_));
    }
    __syncthreads();

    // I1: M=512 -> 32 m-tiles over 8 waves (4 each), N=16, K=64 (2 chunks)
    f32x4 g[4];
    #pragma unroll
    for (int mi = 0; mi < 4; ++mi) g[mi] = (f32x4){0.f, 0.f, 0.f, 0.f};
    #pragma unroll
    for (int ch = 0; ch < 2; ++ch) {
        short8 bh = *(const short8*)&Bs[ch * 1024 + lane * 8];
        short8 bl = *(const short8*)&Bs[ch * 1024 + 512 + lane * 8];
        #pragma unroll
        for (int mi = 0; mi < 4; ++mi) {
            const int mtG = w * 4 + mi;
            short8 ah = *(const short8*)&Fr[(size_t)(160 + mtG * 4 + ch) * 512 + lane * 8];
            short8 al = *(const short8*)&Fr[(size_t)(160 + mtG * 4 + 2 + ch) * 512 + lane * 8];
            g[mi] = __builtin_amdgcn_mfma_f32_16x16x32_bf16(al, bh, g[mi], 0, 0, 0);
            g[mi] = __builtin_amdgcn_mfma_f32_16x16x32_bf16(ah, bl, g[mi], 0, 0, 0);
            g[mi] = __builtin_amdgcn_mfma_f32_16x16x32_bf16(ah, bh, g[mi], 0, 0, 0);
        }
    }

    // repack G (rows m1 = 2h+ri, col ky=n) into I2 A-frag layout: A[h][k2=2ky+ri]
    // wave w writes h in [w*32, w*32+32) -> exactly the ht tiles {2w, 2w+1} it consumes below
    #pragma unroll
    for (int mi = 0; mi < 4; ++mi)
        #pragma unroll
        for (int r = 0; r < 4; ++r) {
            const int m1 = (w * 4 + mi) * 16 + q * 4 + r;
            const int h = m1 >> 1, ri = m1 & 1;
            const int k2 = 2 * n + ri;
            const int ht = h >> 4, hr = h & 15;
            const int ad = ((k2 >> 3) * 16 + hr) * 8 + (k2 & 7);
            const float v = g[mi][r];
            const ushort hi = f2bf(v);
            As[ht * 1024 + ad]       = hi;
            As[ht * 1024 + 512 + ad] = f2bf(v - bf2f(hi));
        }
    __syncthreads();

    // I2: M=256 (16 m-tiles over 8 waves, 2 each), N=256 (16 n-tiles), K=32 (1 chunk)
    #pragma unroll
    for (int mi2 = 0; mi2 < 2; ++mi2) {
        const int ht2 = w * 2 + mi2;
        short8 ah = *(const short8*)&As[ht2 * 1024 + lane * 8];
        short8 al = *(const short8*)&As[ht2 * 1024 + 512 + lane * 8];
        f32x4 a3[16];
        #pragma unroll
        for (int nt = 0; nt < 16; ++nt) a3[nt] = (f32x4){0.f, 0.f, 0.f, 0.f};
        #pragma unroll
        for (int nt = 0; nt < 16; ++nt) {
            short8 bh = *(const short8*)&Fr[(size_t)(288 + nt * 2) * 512 + lane * 8];
            short8 bl = *(const short8*)&Fr[(size_t)(288 + nt * 2 + 1) * 512 + lane * 8];
            a3[nt] = __builtin_amdgcn_mfma_f32_16x16x32_bf16(al, bh, a3[nt], 0, 0, 0);
            a3[nt] = __builtin_amdgcn_mfma_f32_16x16x32_bf16(ah, bl, a3[nt], 0, 0, 0);
            a3[nt] = __builtin_amdgcn_mfma_f32_16x16x32_bf16(ah, bh, a3[nt], 0, 0, 0);
        }
        const size_t Rrow = (size_t)bo * 256 + ht2 * 16 + q * 4;
        #pragma unroll
        for (int nt = 0; nt < 16; ++nt)
            #pragma unroll
            for (int r = 0; r < 4; ++r)
                out[(Rrow + r) * 256 + nt * 16 + n] = a3[nt][r];
    }
}

extern "C" void kernel_launch(void* const* d_in, const int* in_sizes, int n_in,
                              void* d_out, int out_size, void* d_ws, size_t ws_size,
                              hipStream_t stream) {
    const float* x   = (const float*)d_in[0];
    const float* w1r = (const float*)d_in[1];
    const float* w1i = (const float*)d_in[2];
    const float* w2r = (const float*)d_in[3];
    const float* w2i = (const float*)d_in[4];
    float* out = (float*)d_out;

    // ws: Fr 320KB @0 | X 2MB @1MB
    ushort* Fr = (ushort*)d_ws;
    float*  X  = (float*)((char*)d_ws + (1u << 20));

    init_frags<<<320,  512, 0, stream>>>(Fr);
    f12_gemm  <<<512,  512, 0, stream>>>(x, Fr, X);
    i12_gemm  <<<512,  512, 0, stream>>>(X, w1r, w1i, w2r, w2i, Fr, out);
}